// Round 1
// baseline (131.664 us; speedup 1.0000x reference)
//
#include <hip/hip_runtime.h>

// SimulatedMaxPool3D: 2x2 stride-2 max over (h,w) of (1,32,64,256,256) f32.
// Output 0: (1,32,64,128,128) f32 = 33,554,432 elems.
// Output 1: scalar h = 256.0f at flat offset 33,554,432.
//
// Memory-bound: 512 MiB read + 128 MiB write. Each thread: 4 x float4 loads
// (2 input rows x 8 cols), 1 x float4 store (4 output cols). Coalesced 16B/lane.

#define PLANES   2048LL        // n*c*d = 1*32*64
#define IN_HW    65536LL       // 256*256
#define OUT_HW   16384LL       // 128*128
#define UNITS_PER_PLANE 4096   // 128 rows * 32 quad-units
#define N_UNITS  (PLANES * UNITS_PER_PLANE)   // 8,388,608
#define OUT_ELEMS 33554432LL

__global__ __launch_bounds__(256) void maxpool2x2_kernel(
    const float* __restrict__ x, float* __restrict__ out) {
    const long long stride = (long long)gridDim.x * blockDim.x;
    for (long long tid = (long long)blockIdx.x * blockDim.x + threadIdx.x;
         tid < N_UNITS; tid += stride) {
        const long long plane = tid >> 12;          // /4096
        const int rem = (int)(tid & 4095);
        const int oh = rem >> 5;                    // output row 0..127
        const int oq = rem & 31;                    // quad unit 0..31 (4 out cols each)

        const float* base = x + plane * IN_HW + (long long)(oh * 2) * 256 + oq * 8;
        const float4 a0 = *reinterpret_cast<const float4*>(base);
        const float4 a1 = *reinterpret_cast<const float4*>(base + 4);
        const float4 b0 = *reinterpret_cast<const float4*>(base + 256);
        const float4 b1 = *reinterpret_cast<const float4*>(base + 260);

        float4 r;
        r.x = fmaxf(fmaxf(a0.x, a0.y), fmaxf(b0.x, b0.y));
        r.y = fmaxf(fmaxf(a0.z, a0.w), fmaxf(b0.z, b0.w));
        r.z = fmaxf(fmaxf(a1.x, a1.y), fmaxf(b1.x, b1.y));
        r.w = fmaxf(fmaxf(a1.z, a1.w), fmaxf(b1.z, b1.w));

        *reinterpret_cast<float4*>(out + plane * OUT_HW + (long long)oh * 128 + oq * 4) = r;
    }
    if (blockIdx.x == 0 && threadIdx.x == 0) {
        out[OUT_ELEMS] = 256.0f;   // second tuple output: h = x.shape[3]
    }
}

extern "C" void kernel_launch(void* const* d_in, const int* in_sizes, int n_in,
                              void* d_out, int out_size, void* d_ws, size_t ws_size,
                              hipStream_t stream) {
    const float* x = (const float*)d_in[0];
    float* out = (float*)d_out;
    // Memory-bound: cap grid at 2048 blocks, grid-stride the rest (G11).
    maxpool2x2_kernel<<<2048, 256, 0, stream>>>(x, out);
}